// Round 2
// baseline (6259.081 us; speedup 1.0000x reference)
//
#include <hip/hip_runtime.h>

#define TT 1024
#define SS 64
#define HH 256

// One block = 256 threads (thread == hidden neuron h), handles 2 batches.
// Per timestep: wave-uniform 64-bit spike mask via ballot; masked sum of the
// per-thread W_h row (64 regs) via scalar-select + v_fmac; LIF update; 64-lane
// shfl_xor reduce of s_h*W_o into LDS partials; single barrier at end; 2 lanes
// run the sequential v_o / output-spike scan.
__launch_bounds__(256, 4)
__global__ void snn_kernel(const float* __restrict__ sensor,
                           const float* __restrict__ noise,
                           const float* __restrict__ Wh,
                           const float* __restrict__ bh,
                           const float* __restrict__ Wo,
                           const float* __restrict__ bo,
                           float* __restrict__ out)
{
    __shared__ float part[TT][4][2];   // [t][wave][batch] = 32 KiB

    const int tid  = threadIdx.x;
    const int lane = tid & 63;
    const int wave = tid >> 6;
    const int h    = tid;
    const int bb   = blockIdx.x * 2;

    // W_h row for this neuron: 64 floats in registers
    float w[SS];
    {
        const float4* wrow = reinterpret_cast<const float4*>(Wh + (size_t)h * SS);
        #pragma unroll
        for (int i = 0; i < SS / 4; ++i) {
            float4 v = wrow[i];
            w[4 * i + 0] = v.x; w[4 * i + 1] = v.y;
            w[4 * i + 2] = v.z; w[4 * i + 3] = v.w;
        }
    }
    const float bhv = bh[h];
    const float wov = Wo[h];

    const float beta_h = expf(-1.0f / 50.0f);   // constant-folded fp32
    const float beta_o = expf(-1.0f / 30.0f);

    float vh0 = 0.0f, vh1 = 0.0f;

    const float* s0p = sensor + (size_t)(bb + 0) * TT * SS + lane;
    const float* s1p = sensor + (size_t)(bb + 1) * TT * SS + lane;
    const float* n0p = noise  + (size_t)(bb + 0) * TT * SS + lane;
    const float* n1p = noise  + (size_t)(bb + 1) * TT * SS + lane;

    // prefetch t = 0
    float cs0 = s0p[0], cn0 = n0p[0];
    float cs1 = s1p[0], cn1 = n1p[0];

    for (int t = 0; t < TT; ++t) {
        // prefetch t+1 (clamped; redundant harmless load at the last step)
        const int tn = (t + 1 < TT) ? (t + 1) : (TT - 1);
        float ps0 = s0p[(size_t)tn * SS];
        float pn0 = n0p[(size_t)tn * SS];
        float ps1 = s1p[(size_t)tn * SS];
        float pn1 = n1p[(size_t)tn * SS];

        // stochastic rate coding -> wave-uniform 64-bit spike masks
        unsigned long long m0 = __ballot(cn0 < cs0);
        unsigned long long m1 = __ballot(cn1 < cs1);

        // masked row-sum: dot[b] = sum_{s in mask_b} w[s]
        // two accumulators per batch for FMA-latency ILP
        float d0a = 0.0f, d0b = 0.0f, d1a = 0.0f, d1b = 0.0f;
        #pragma unroll
        for (int s = 0; s < SS; s += 2) {
            float sp0a = ((m0 >> s) & 1ull)       ? 1.0f : 0.0f;
            float sp0b = ((m0 >> (s + 1)) & 1ull) ? 1.0f : 0.0f;
            float sp1a = ((m1 >> s) & 1ull)       ? 1.0f : 0.0f;
            float sp1b = ((m1 >> (s + 1)) & 1ull) ? 1.0f : 0.0f;
            d0a += sp0a * w[s];
            d0b += sp0b * w[s + 1];
            d1a += sp1a * w[s];
            d1b += sp1b * w[s + 1];
        }
        float dot0 = d0a + d0b;
        float dot1 = d1a + d1b;

        // hidden LIF: integrate, threshold, hard reset
        vh0 = (beta_h * vh0 + dot0) + bhv;
        vh1 = (beta_h * vh1 + dot1) + bhv;
        float sh0 = (vh0 >= 1.0f) ? 1.0f : 0.0f;
        float sh1 = (vh1 >= 1.0f) ? 1.0f : 0.0f;
        vh0 = (vh0 >= 1.0f) ? 0.0f : vh0;
        vh1 = (vh1 >= 1.0f) ? 0.0f : vh1;

        // per-wave partial of s_h @ W_o^T (64-lane butterfly sum)
        float r0 = sh0 * wov;
        float r1 = sh1 * wov;
        #pragma unroll
        for (int off = 1; off < 64; off <<= 1) {
            r0 += __shfl_xor(r0, off);
            r1 += __shfl_xor(r1, off);
        }
        if (lane == 0) {
            part[t][wave][0] = r0;
            part[t][wave][1] = r1;
        }

        cs0 = ps0; cn0 = pn0; cs1 = ps1; cn1 = pn1;
    }

    __syncthreads();

    // sequential output-LIF scan, one lane per batch
    if (tid < 2) {
        const int b = tid;
        const float bov = bo[0];
        float vo = 0.0f, acc = 0.0f;
        for (int t = 0; t < TT; ++t) {
            float r = ((part[t][0][b] + part[t][1][b]) + part[t][2][b]) + part[t][3][b];
            vo = (beta_o * vo + r) + bov;
            float so = (vo >= 1.0f) ? 1.0f : 0.0f;
            vo = (vo >= 1.0f) ? 0.0f : vo;
            acc += so;
        }
        out[bb + b] = acc * (1.0f / 1024.0f);
    }
}

extern "C" void kernel_launch(void* const* d_in, const int* in_sizes, int n_in,
                              void* d_out, int out_size, void* d_ws, size_t ws_size,
                              hipStream_t stream)
{
    const float* sensor = (const float*)d_in[0];
    const float* noise  = (const float*)d_in[1];
    const float* Wh     = (const float*)d_in[2];
    const float* bh     = (const float*)d_in[3];
    const float* Wo     = (const float*)d_in[4];
    const float* bo     = (const float*)d_in[5];
    float* out = (float*)d_out;

    const int B = in_sizes[0] / (TT * SS);   // 2048
    dim3 grid(B / 2), block(256);
    hipLaunchKernelGGL(snn_kernel, grid, block, 0, stream,
                       sensor, noise, Wh, bh, Wo, bo, out);
}

// Round 3
// 413.999 us; speedup vs baseline: 15.1186x; 15.1186x over previous
//
#include <hip/hip_runtime.h>

#define TT 1024
#define SS 64
#define HH 256
#define BB 4            // batches per block
#define TC 16           // timesteps per chunk
#define NCHUNK (TT / TC)
#define MROWS (BB * TC) // 64 GEMM rows per chunk

typedef _Float16 f16x8 __attribute__((ext_vector_type(8)));
typedef float    f32x4 __attribute__((ext_vector_type(4)));

// Fused SNN: per chunk of 16 timesteps ->
//   P1: staged global loads -> fp16 spikes (exact 0/1) in XOR-swizzled LDS
//   P2: MFMA 16x16x32_f16, W_h as 2-term fp16 split (hi + lo/2048, err ~2^-22)
//   P3: register LIF scan over 16 t (parallel over b,h), ILP'd 4-level shfl
//   P4: 4 lanes run the sequential output-LIF over the chunk
// 74 KB LDS, 512 threads, launch_bounds caps VGPR<=128 -> 2 blocks/CU.
__launch_bounds__(512, 4)
__global__ void snn_mfma(const float* __restrict__ sensor,
                         const float* __restrict__ noise,
                         const float* __restrict__ Wh,
                         const float* __restrict__ bh,
                         const float* __restrict__ Wo,
                         const float* __restrict__ bo,
                         float* __restrict__ out)
{
    __shared__ __align__(16) _Float16 spk[MROWS * SS];   // 8 KB
    __shared__ float dot_s[MROWS * HH];                  // 64 KB
    __shared__ float rpart[TC][BB][8];                   // 2 KB

    const int tid  = threadIdx.x;
    const int lane = tid & 63;
    const int wave = tid >> 6;
    const int b0   = blockIdx.x * BB;

    // ---- W_h fragments (persistent, registers): wave owns n-tiles {wave, wave+8}
    f16x8 whi[2][2], wlo[2][2];   // [ntile][khalf]
    #pragma unroll
    for (int nti = 0; nti < 2; ++nti) {
        const int h = (wave + nti * 8) * 16 + (lane & 15);
        #pragma unroll
        for (int kh = 0; kh < 2; ++kh) {
            const int k = kh * 32 + (lane >> 4) * 8;
            const float* p = Wh + (size_t)h * SS + k;
            float4 wa = *(const float4*)(p);
            float4 wb = *(const float4*)(p + 4);
            float wv[8] = {wa.x, wa.y, wa.z, wa.w, wb.x, wb.y, wb.z, wb.w};
            f16x8 fh, fl;
            #pragma unroll
            for (int j = 0; j < 8; ++j) {
                _Float16 hi = (_Float16)wv[j];
                float r1 = wv[j] - (float)hi;
                _Float16 lo = (_Float16)(r1 * 2048.0f);
                fh[j] = hi; fl[j] = lo;
            }
            whi[nti][kh] = fh; wlo[nti][kh] = fl;
        }
    }

    // ---- P3 persistent state: thread owns (b = tid>>7, h in {i, i+128})
    const int pb = tid >> 7;
    const int pi = tid & 127;
    const float bh0 = bh[pi], bh1 = bh[pi + 128];
    const float wo0 = Wo[pi], wo1 = Wo[pi + 128];
    float vh0 = 0.0f, vh1 = 0.0f;

    // ---- P4 state (lanes tid<4 of wave 0)
    const float bov = bo[0];
    float vo = 0.0f, accO = 0.0f;

    const float betah = expf(-1.0f / 50.0f);
    const float betao = expf(-1.0f / 30.0f);

    // ---- P1 staging: thread stages row srow (= b*16+t), 8-float group ssg
    const int srow = tid >> 3;
    const int ssg  = tid & 7;
    const int sb   = srow >> 4;
    const int st   = srow & 15;
    const float* sgp = sensor + ((size_t)(b0 + sb) * TT + st) * SS + ssg * 8;
    const float* ngp = noise  + ((size_t)(b0 + sb) * TT + st) * SS + ssg * 8;
    const int sbyte = (srow * 128 + ssg * 16) ^ ((srow & 7) << 4);

    // prologue: stage chunk 0
    float4 sA = *(const float4*)(sgp);
    float4 sB = *(const float4*)(sgp + 4);
    float4 nA = *(const float4*)(ngp);
    float4 nB = *(const float4*)(ngp + 4);

    for (int c = 0; c < NCHUNK; ++c) {
        // P1: spikes from staged regs -> swizzled LDS (one b128 store)
        {
            f16x8 sv;
            sv[0] = (nA.x < sA.x) ? (_Float16)1.0f : (_Float16)0.0f;
            sv[1] = (nA.y < sA.y) ? (_Float16)1.0f : (_Float16)0.0f;
            sv[2] = (nA.z < sA.z) ? (_Float16)1.0f : (_Float16)0.0f;
            sv[3] = (nA.w < sA.w) ? (_Float16)1.0f : (_Float16)0.0f;
            sv[4] = (nB.x < sB.x) ? (_Float16)1.0f : (_Float16)0.0f;
            sv[5] = (nB.y < sB.y) ? (_Float16)1.0f : (_Float16)0.0f;
            sv[6] = (nB.z < sB.z) ? (_Float16)1.0f : (_Float16)0.0f;
            sv[7] = (nB.w < sB.w) ? (_Float16)1.0f : (_Float16)0.0f;
            *(f16x8*)((char*)spk + sbyte) = sv;
        }
        // prefetch next chunk into staging regs (overlaps P2/P3)
        if (c + 1 < NCHUNK) {
            const float* ps = sgp + (size_t)(c + 1) * TC * SS;
            const float* pn = ngp + (size_t)(c + 1) * TC * SS;
            sA = *(const float4*)(ps);
            sB = *(const float4*)(ps + 4);
            nA = *(const float4*)(pn);
            nB = *(const float4*)(pn + 4);
        }
        __syncthreads();   // B1: spikes ready; dot free

        // P2: GEMM  dot[m=(b,t)][h] = spikes[m][k] @ Wh[h][k]^T
        #pragma unroll
        for (int nti = 0; nti < 2; ++nti) {
            const int hcol = (wave + nti * 8) * 16 + (lane & 15);
            #pragma unroll
            for (int mb = 0; mb < 4; ++mb) {
                const int arow  = mb * 16 + (lane & 15);
                const int ab0   = (arow * 128 + (lane >> 4) * 16) ^ ((arow & 7) << 4);
                f16x8 a0 = *(const f16x8*)((const char*)spk + ab0);
                f16x8 a1 = *(const f16x8*)((const char*)spk + (ab0 + 64));
                f32x4 ah = {0.0f, 0.0f, 0.0f, 0.0f};
                f32x4 al = {0.0f, 0.0f, 0.0f, 0.0f};
                ah = __builtin_amdgcn_mfma_f32_16x16x32_f16(a0, whi[nti][0], ah, 0, 0, 0);
                ah = __builtin_amdgcn_mfma_f32_16x16x32_f16(a1, whi[nti][1], ah, 0, 0, 0);
                al = __builtin_amdgcn_mfma_f32_16x16x32_f16(a0, wlo[nti][0], al, 0, 0, 0);
                al = __builtin_amdgcn_mfma_f32_16x16x32_f16(a1, wlo[nti][1], al, 0, 0, 0);
                #pragma unroll
                for (int r = 0; r < 4; ++r) {
                    const int row = mb * 16 + (lane >> 4) * 4 + r;
                    dot_s[row * HH + hcol] = ah[r] + al[r] * (1.0f / 2048.0f);
                }
            }
        }
        __syncthreads();   // B2: dot ready

        // P3: LIF scan, 16 t in registers; shuffles pipelined across t
        float r[TC];
        #pragma unroll
        for (int t = 0; t < TC; ++t) {
            const float d0 = dot_s[(pb * TC + t) * HH + pi];
            const float d1 = dot_s[(pb * TC + t) * HH + pi + 128];
            vh0 = (betah * vh0 + d0) + bh0;
            vh1 = (betah * vh1 + d1) + bh1;
            const float s0 = (vh0 >= 1.0f) ? 1.0f : 0.0f;
            vh0 = (vh0 >= 1.0f) ? 0.0f : vh0;
            const float s1 = (vh1 >= 1.0f) ? 1.0f : 0.0f;
            vh1 = (vh1 >= 1.0f) ? 0.0f : vh1;
            r[t] = s0 * wo0 + s1 * wo1;
        }
        #pragma unroll
        for (int t = 0; t < TC; ++t) r[t] += __shfl_xor(r[t], 1);
        #pragma unroll
        for (int t = 0; t < TC; ++t) r[t] += __shfl_xor(r[t], 2);
        #pragma unroll
        for (int t = 0; t < TC; ++t) r[t] += __shfl_xor(r[t], 4);
        #pragma unroll
        for (int t = 0; t < TC; ++t) r[t] += __shfl_xor(r[t], 8);
        if ((lane & 15) == 0) {
            #pragma unroll
            for (int t = 0; t < TC; ++t)
                rpart[t][pb][(wave & 1) * 4 + (lane >> 4)] = r[t];
        }
        __syncthreads();   // B3: rpart ready

        // P4: sequential output LIF for this chunk (4 lanes; others loop on)
        if (tid < BB) {
            #pragma unroll
            for (int t = 0; t < TC; ++t) {
                float rr = rpart[t][tid][0];
                rr += rpart[t][tid][1]; rr += rpart[t][tid][2];
                rr += rpart[t][tid][3]; rr += rpart[t][tid][4];
                rr += rpart[t][tid][5]; rr += rpart[t][tid][6];
                rr += rpart[t][tid][7];
                vo = (betao * vo + rr) + bov;
                const float so = (vo >= 1.0f) ? 1.0f : 0.0f;
                vo = (vo >= 1.0f) ? 0.0f : vo;
                accO += so;
            }
        }
    }

    if (tid < BB) out[b0 + tid] = accO * (1.0f / 1024.0f);
}

extern "C" void kernel_launch(void* const* d_in, const int* in_sizes, int n_in,
                              void* d_out, int out_size, void* d_ws, size_t ws_size,
                              hipStream_t stream)
{
    const float* sensor = (const float*)d_in[0];
    const float* noise  = (const float*)d_in[1];
    const float* Wh     = (const float*)d_in[2];
    const float* bh     = (const float*)d_in[3];
    const float* Wo     = (const float*)d_in[4];
    const float* bo     = (const float*)d_in[5];
    float* out = (float*)d_out;

    const int B = in_sizes[0] / (TT * SS);   // 2048
    dim3 grid(B / BB), block(512);
    hipLaunchKernelGGL(snn_mfma, grid, block, 0, stream,
                       sensor, noise, Wh, bh, Wo, bo, out);
}

// Round 4
// 269.542 us; speedup vs baseline: 23.2212x; 1.5359x over previous
//
#include <hip/hip_runtime.h>

#define TT 1024
#define SS 64
#define HH 256
#define BB 4            // batches per block
#define TC 16           // timesteps per chunk
#define NC (TT / TC)    // 64 chunks

typedef _Float16 f16x8 __attribute__((ext_vector_type(8)));
typedef float    f32x4 __attribute__((ext_vector_type(4)));

// ---- DPP helpers (VALU-pipe cross-lane, no DS ops) ----
template <int CTRL>
__device__ __forceinline__ float dpp_add(float x) {
    int v = __float_as_int(x);
    int m = __builtin_amdgcn_update_dpp(v, v, CTRL, 0xF, 0xF, true);
    return x + __int_as_float(m);
}
// full sum across the 16 lanes of a DPP row (all lanes end with the sum)
__device__ __forceinline__ float rowsum16(float x) {
    x = dpp_add<0xB1>(x);    // quad_perm [1,0,3,2]  : + lane^1
    x = dpp_add<0x4E>(x);    // quad_perm [2,3,0,1]  : + lane^2
    x = dpp_add<0x141>(x);   // row_half_mirror      : + partner quad (8-sum)
    x = dpp_add<0x140>(x);   // row_mirror           : + partner half (16-sum)
    return x;
}
// sum over the 4 "wx" slots within a row while preserving lane&3; then caller
// adds the cross-row half via shfl_xor(16).
__device__ __forceinline__ float wxsum_row(float x) {
    x = dpp_add<0x124>(x);   // row_ror:4
    x = dpp_add<0x128>(x);   // row_ror:8
    return x;
}

// Fused SNN, m = (batch*4 + tq) MFMA rows:
//  - spikes: global -> regs (prefetch 2 chunks ahead) -> 8KB XOR-swizzled f16 LDS
//  - hidden dot: mfma_f32_16x16x32_f16, W_h as hi + lo/2048 (err ~2^-22, proven exact r3)
//  - hidden LIF: fully in-register (lane owns batch=lane>>4, h=lane&15(+tiles) forever)
//  - output partial: DPP rowsum16 (no DS), 4 b128 stores/wave/chunk to 4KB rpart
//  - output LIF: lag-1 pipelined on waves 0..3 (one batch each), ONE barrier/chunk
__launch_bounds__(512, 4)
__global__ void snn_fused(const float* __restrict__ sensor,
                          const float* __restrict__ noise,
                          const float* __restrict__ Wh,
                          const float* __restrict__ bh,
                          const float* __restrict__ Wo,
                          const float* __restrict__ bo,
                          float* __restrict__ out)
{
    __shared__ __align__(16) char  spk[2][4 * 16 * 128];   // [buf][(tw*16+m)*128B] swizzled, 16 KB
    __shared__ __align__(16) float rpart[2][BB][8][TC];    // [buf][b][wave][t], 4 KB

    const int tid  = threadIdx.x;
    const int lane = tid & 63;
    const int wave = tid >> 6;
    const int b0   = blockIdx.x * BB;

    // ---- persistent W_h fragments: wave owns h-tiles {wave, wave+8}
    f16x8 whi[2][2], wlo[2][2];   // [nti][khalf]
    #pragma unroll
    for (int nti = 0; nti < 2; ++nti) {
        const int h = (wave + nti * 8) * 16 + (lane & 15);
        #pragma unroll
        for (int kh = 0; kh < 2; ++kh) {
            const int k = kh * 32 + (lane >> 4) * 8;
            const float* p = Wh + (size_t)h * SS + k;
            float4 wa = *(const float4*)(p);
            float4 wb = *(const float4*)(p + 4);
            float wv[8] = {wa.x, wa.y, wa.z, wa.w, wb.x, wb.y, wb.z, wb.w};
            f16x8 fh, fl;
            #pragma unroll
            for (int j = 0; j < 8; ++j) {
                _Float16 hi = (_Float16)wv[j];
                float r1 = wv[j] - (float)hi;
                fh[j] = hi;
                fl[j] = (_Float16)(r1 * 2048.0f);
            }
            whi[nti][kh] = fh; wlo[nti][kh] = fl;
        }
    }

    const int hc = lane & 15;
    const float bh0 = bh[wave * 16 + hc], bh1 = bh[128 + wave * 16 + hc];
    const float wo0 = Wo[wave * 16 + hc], wo1 = Wo[128 + wave * 16 + hc];
    const float bov = bo[0];
    const float betah = expf(-1.0f / 50.0f);
    const float betao = expf(-1.0f / 30.0f);

    float vh0 = 0.0f, vh1 = 0.0f;   // hidden state: batch=lane>>4, h tiles {wave,wave+8}
    float vo = 0.0f, acc = 0.0f;    // output state (waves 0..3 only)

    // ---- spike-writer decomposition: tid -> (tw, m, oct)
    const int wtw  = tid >> 7;          // 0..3
    const int wm   = (tid >> 3) & 15;   // m = b*4 + tq
    const int woct = tid & 7;
    const int wrow = wtw * 16 + wm;
    const int wbyte = wrow * 128 + ((woct * 16) ^ ((wrow & 7) << 4));
    const float* sgp = sensor + ((size_t)(b0 + (wm >> 2)) * TT + wtw * 4 + (wm & 3)) * SS + woct * 8;
    const float* ngp = noise  + ((size_t)(b0 + (wm >> 2)) * TT + wtw * 4 + (wm & 3)) * SS + woct * 8;

    // staged next-chunk data (prefetch regs)
    float4 sA, sB, nA, nB;

    auto pack_spk = [&](char* dst) {
        f16x8 sv;
        sv[0] = (nA.x < sA.x) ? (_Float16)1.0f : (_Float16)0.0f;
        sv[1] = (nA.y < sA.y) ? (_Float16)1.0f : (_Float16)0.0f;
        sv[2] = (nA.z < sA.z) ? (_Float16)1.0f : (_Float16)0.0f;
        sv[3] = (nA.w < sA.w) ? (_Float16)1.0f : (_Float16)0.0f;
        sv[4] = (nB.x < sB.x) ? (_Float16)1.0f : (_Float16)0.0f;
        sv[5] = (nB.y < sB.y) ? (_Float16)1.0f : (_Float16)0.0f;
        sv[6] = (nB.z < sB.z) ? (_Float16)1.0f : (_Float16)0.0f;
        sv[7] = (nB.w < sB.w) ? (_Float16)1.0f : (_Float16)0.0f;
        *(f16x8*)(dst + wbyte) = sv;
    };

    // output-LIF step over one chunk's rpart slab (waves 0..3, batch = wave)
    auto p4_step = [&](const float (*rp)[TC]) {
        const int wx  = (lane >> 2) & 7;
        const int twq = lane & 3;
        float4 q = *(const float4*)&rp[wx][twq * 4];
        q.x = wxsum_row(q.x); q.x += __shfl_xor(q.x, 16);
        q.y = wxsum_row(q.y); q.y += __shfl_xor(q.y, 16);
        q.z = wxsum_row(q.z); q.z += __shfl_xor(q.z, 16);
        q.w = wxsum_row(q.w); q.w += __shfl_xor(q.w, 16);
        // lanes with lane&3==ph hold r[t=ph*4 .. +3]; serial scan with handoff
        #pragma unroll
        for (int ph = 0; ph < 4; ++ph) {
            if ((lane & 3) == ph) {
                float so;
                vo = (betao * vo + q.x) + bov; so = (vo >= 1.0f) ? 1.0f : 0.0f; vo = (vo >= 1.0f) ? 0.0f : vo; acc += so;
                vo = (betao * vo + q.y) + bov; so = (vo >= 1.0f) ? 1.0f : 0.0f; vo = (vo >= 1.0f) ? 0.0f : vo; acc += so;
                vo = (betao * vo + q.z) + bov; so = (vo >= 1.0f) ? 1.0f : 0.0f; vo = (vo >= 1.0f) ? 0.0f : vo; acc += so;
                vo = (betao * vo + q.w) + bov; so = (vo >= 1.0f) ? 1.0f : 0.0f; vo = (vo >= 1.0f) ? 0.0f : vo; acc += so;
            }
            vo  = __shfl(vo, ph);
            acc = __shfl(acc, ph);
        }
    };

    // ---- prologue: chunk 0 -> LDS buf0; chunk 1 -> staged regs
    sA = *(const float4*)(sgp);     sB = *(const float4*)(sgp + 4);
    nA = *(const float4*)(ngp);     nB = *(const float4*)(ngp + 4);
    pack_spk(spk[0]);
    {
        const float* ps = sgp + (size_t)1 * TC * SS;
        const float* pn = ngp + (size_t)1 * TC * SS;
        sA = *(const float4*)(ps);  sB = *(const float4*)(ps + 4);
        nA = *(const float4*)(pn);  nB = *(const float4*)(pn + 4);
    }
    __syncthreads();

    const int aoct = lane >> 4;
    const int asw  = (hc & 7) << 4;

    for (int c = 0; c < NC; ++c) {
        const int cur = c & 1;

        // A: pack chunk c+1 (staged) -> other buffer (safe: its readers finished pre-barrier)
        if (c + 1 < NC) pack_spk(spk[cur ^ 1]);

        // B: issue global loads for chunk c+2 (in flight under this chunk's compute)
        if (c + 2 < NC) {
            const float* ps = sgp + (size_t)(c + 2) * TC * SS;
            const float* pn = ngp + (size_t)(c + 2) * TC * SS;
            sA = *(const float4*)(ps);  sB = *(const float4*)(ps + 4);
            nA = *(const float4*)(pn);  nB = *(const float4*)(pn + 4);
        }

        // P4: output LIF for chunk c-1 (lag-1; rpart[cur^1] synced by last barrier)
        if (c > 0 && wave < 4) p4_step(rpart[cur ^ 1][wave]);

        // C: compute chunk c
        const char* sp = spk[cur];
        for (int tw = 0; tw < 4; ++tw) {
            const int rb = (tw * 16 + hc) * 128;
            f16x8 a0 = *(const f16x8*)(sp + rb + ((aoct * 16) ^ asw));
            f16x8 a1 = *(const f16x8*)(sp + rb + (((aoct + 4) * 16) ^ asw));
            f32x4 ah0 = {0,0,0,0}, al0 = {0,0,0,0}, ah1 = {0,0,0,0}, al1 = {0,0,0,0};
            ah0 = __builtin_amdgcn_mfma_f32_16x16x32_f16(a0, whi[0][0], ah0, 0, 0, 0);
            ah0 = __builtin_amdgcn_mfma_f32_16x16x32_f16(a1, whi[0][1], ah0, 0, 0, 0);
            al0 = __builtin_amdgcn_mfma_f32_16x16x32_f16(a0, wlo[0][0], al0, 0, 0, 0);
            al0 = __builtin_amdgcn_mfma_f32_16x16x32_f16(a1, wlo[0][1], al0, 0, 0, 0);
            ah1 = __builtin_amdgcn_mfma_f32_16x16x32_f16(a0, whi[1][0], ah1, 0, 0, 0);
            ah1 = __builtin_amdgcn_mfma_f32_16x16x32_f16(a1, whi[1][1], ah1, 0, 0, 0);
            al1 = __builtin_amdgcn_mfma_f32_16x16x32_f16(a0, wlo[1][0], al1, 0, 0, 0);
            al1 = __builtin_amdgcn_mfma_f32_16x16x32_f16(a1, wlo[1][1], al1, 0, 0, 0);
            float rcv[4];
            #pragma unroll
            for (int r = 0; r < 4; ++r) {
                const float d0 = ah0[r] + al0[r] * (1.0f / 2048.0f);
                const float d1 = ah1[r] + al1[r] * (1.0f / 2048.0f);
                vh0 = (betah * vh0 + d0) + bh0;
                vh1 = (betah * vh1 + d1) + bh1;
                const float s0 = (vh0 >= 1.0f) ? 1.0f : 0.0f;
                vh0 = (vh0 >= 1.0f) ? 0.0f : vh0;
                const float s1 = (vh1 >= 1.0f) ? 1.0f : 0.0f;
                vh1 = (vh1 >= 1.0f) ? 0.0f : vh1;
                rcv[r] = rowsum16(s0 * wo0 + s1 * wo1);
            }
            if ((lane & 15) == 0) {
                float4 rq = make_float4(rcv[0], rcv[1], rcv[2], rcv[3]);
                *(float4*)&rpart[cur][lane >> 4][wave][tw * 4] = rq;
            }
        }

        __syncthreads();   // the ONE barrier: spk writes, rpart writes all visible
    }

    // epilogue: output LIF for the last chunk, then write results
    if (wave < 4) {
        p4_step(rpart[(NC - 1) & 1][wave]);
        if (lane == 0) out[b0 + wave] = acc * (1.0f / (float)TT);
    }
}

extern "C" void kernel_launch(void* const* d_in, const int* in_sizes, int n_in,
                              void* d_out, int out_size, void* d_ws, size_t ws_size,
                              hipStream_t stream)
{
    const float* sensor = (const float*)d_in[0];
    const float* noise  = (const float*)d_in[1];
    const float* Wh     = (const float*)d_in[2];
    const float* bh     = (const float*)d_in[3];
    const float* Wo     = (const float*)d_in[4];
    const float* bo     = (const float*)d_in[5];
    float* out = (float*)d_out;

    const int B = in_sizes[0] / (TT * SS);   // 2048
    dim3 grid(B / BB), block(512);
    hipLaunchKernelGGL(snn_fused, grid, block, 0, stream,
                       sensor, noise, Wh, bh, Wo, bo, out);
}

// Round 5
// 245.929 us; speedup vs baseline: 25.4508x; 1.0960x over previous
//
#include <hip/hip_runtime.h>

#define TT 1024
#define SS 64
#define HH 256
#define BB 4            // batches per block
#define TC 16           // timesteps per chunk
#define NC (TT / TC)    // 64 chunks

typedef _Float16 f16x8 __attribute__((ext_vector_type(8)));
typedef float    f32x4 __attribute__((ext_vector_type(4)));
typedef unsigned int u32x4 __attribute__((ext_vector_type(4)));

// ---- DPP helpers ----
// builtin path (compiler handles hazards) - used in the cold p4 section
template <int CTRL>
__device__ __forceinline__ float dpp_add(float x) {
    int v = __float_as_int(x);
    int m = __builtin_amdgcn_update_dpp(v, v, CTRL, 0xF, 0xF, true);
    return x + __int_as_float(m);
}
__device__ __forceinline__ float wxsum_row(float x) {
    x = dpp_add<0x124>(x);   // row_ror:4
    x = dpp_add<0x128>(x);   // row_ror:8
    return x;
}

// hot path: single-instruction DPP adds. s_nop 1 covers the
// VALU-write -> DPP-read hazard (compiler can't see inside asm).
__device__ __forceinline__ float rowsum16_asm(float x) {
    float a, b, c, d;
    asm("s_nop 1\n\t"
        "v_add_f32_dpp %0, %1, %1 quad_perm:[1,0,3,2] row_mask:0xf bank_mask:0xf"
        : "=v"(a) : "v"(x));
    asm("s_nop 1\n\t"
        "v_add_f32_dpp %0, %1, %1 quad_perm:[2,3,0,1] row_mask:0xf bank_mask:0xf"
        : "=v"(b) : "v"(a));
    asm("s_nop 1\n\t"
        "v_add_f32_dpp %0, %1, %1 row_half_mirror row_mask:0xf bank_mask:0xf"
        : "=v"(c) : "v"(b));
    asm("s_nop 1\n\t"
        "v_add_f32_dpp %0, %1, %1 row_mirror row_mask:0xf bank_mask:0xf"
        : "=v"(d) : "v"(c));
    return d;
}

__launch_bounds__(512, 4)
__global__ void snn_fused(const float* __restrict__ sensor,
                          const float* __restrict__ noise,
                          const float* __restrict__ Wh,
                          const float* __restrict__ bh,
                          const float* __restrict__ Wo,
                          const float* __restrict__ bo,
                          float* __restrict__ out)
{
    __shared__ __align__(16) char  spk[2][4 * 16 * 128];   // swizzled f16 spikes, 16 KB
    __shared__ __align__(16) float rpart[2][BB][8][TC];    // [buf][b][wave][t], 4 KB

    const int tid  = threadIdx.x;
    const int lane = tid & 63;
    const int wave = tid >> 6;
    const int b0   = blockIdx.x * BB;

    // ---- persistent W_h fragments: wave owns h-tiles {wave, wave+8}
    f16x8 whi[2][2], wlo[2][2];   // [nti][khalf]
    #pragma unroll
    for (int nti = 0; nti < 2; ++nti) {
        const int h = (wave + nti * 8) * 16 + (lane & 15);
        #pragma unroll
        for (int kh = 0; kh < 2; ++kh) {
            const int k = kh * 32 + (lane >> 4) * 8;
            const float* p = Wh + (size_t)h * SS + k;
            float4 wa = *(const float4*)(p);
            float4 wb = *(const float4*)(p + 4);
            float wv[8] = {wa.x, wa.y, wa.z, wa.w, wb.x, wb.y, wb.z, wb.w};
            f16x8 fh, fl;
            #pragma unroll
            for (int j = 0; j < 8; ++j) {
                _Float16 hi = (_Float16)wv[j];
                float r1 = wv[j] - (float)hi;
                fh[j] = hi;
                fl[j] = (_Float16)(r1 * 2048.0f);
            }
            whi[nti][kh] = fh; wlo[nti][kh] = fl;
        }
    }

    const int hc = lane & 15;
    const float bh0 = bh[wave * 16 + hc], bh1 = bh[128 + wave * 16 + hc];
    const float wo0 = Wo[wave * 16 + hc], wo1 = Wo[128 + wave * 16 + hc];
    const float bov = bo[0];
    const float betah = expf(-1.0f / 50.0f);
    const float betao = expf(-1.0f / 30.0f);

    const f32x4 zero4 = {0.0f, 0.0f, 0.0f, 0.0f};   // persistent MFMA C operand

    float vh0 = 0.0f, vh1 = 0.0f;   // hidden state: batch=lane>>4, h tiles {wave,wave+8}
    float vo = 0.0f, acc = 0.0f;    // output state (waves 0..3 only)

    // ---- spike-writer decomposition: tid -> (tw, m, oct)
    const int wtw  = tid >> 7;          // 0..3
    const int wm   = (tid >> 3) & 15;   // m = b*4 + tq
    const int woct = tid & 7;
    const int wrow = wtw * 16 + wm;
    const int wbyte = wrow * 128 + ((woct * 16) ^ ((wrow & 7) << 4));
    const float* sgp = sensor + ((size_t)(b0 + (wm >> 2)) * TT + wtw * 4 + (wm & 3)) * SS + woct * 8;
    const float* ngp = noise  + ((size_t)(b0 + (wm >> 2)) * TT + wtw * 4 + (wm & 3)) * SS + woct * 8;

    // staged next-chunk data (prefetch regs)
    float4 sA, sB, nA, nB;

    // integer spike pack: u16 one = 0x3C00 (f16 1.0); no cvt chain
    auto pack_spk = [&](char* dst) {
        u32x4 sv;
        sv[0] = (nA.x < sA.x ? 0x3C00u : 0u) | (nA.y < sA.y ? 0x3C000000u : 0u);
        sv[1] = (nA.z < sA.z ? 0x3C00u : 0u) | (nA.w < sA.w ? 0x3C000000u : 0u);
        sv[2] = (nB.x < sB.x ? 0x3C00u : 0u) | (nB.y < sB.y ? 0x3C000000u : 0u);
        sv[3] = (nB.z < sB.z ? 0x3C00u : 0u) | (nB.w < sB.w ? 0x3C000000u : 0u);
        *(u32x4*)(dst + wbyte) = sv;
    };

    // output-LIF step over one chunk's rpart slab (waves 0..3, batch = wave)
    auto p4_step = [&](const float (*rp)[TC]) {
        const int wx  = (lane >> 2) & 7;
        const int twq = lane & 3;
        float4 q = *(const float4*)&rp[wx][twq * 4];
        q.x = wxsum_row(q.x); q.x += __shfl_xor(q.x, 16);
        q.y = wxsum_row(q.y); q.y += __shfl_xor(q.y, 16);
        q.z = wxsum_row(q.z); q.z += __shfl_xor(q.z, 16);
        q.w = wxsum_row(q.w); q.w += __shfl_xor(q.w, 16);
        #pragma unroll
        for (int ph = 0; ph < 4; ++ph) {
            if ((lane & 3) == ph) {
                float so;
                vo = (betao * vo + q.x) + bov; so = (vo >= 1.0f) ? 1.0f : 0.0f; vo = (vo >= 1.0f) ? 0.0f : vo; acc += so;
                vo = (betao * vo + q.y) + bov; so = (vo >= 1.0f) ? 1.0f : 0.0f; vo = (vo >= 1.0f) ? 0.0f : vo; acc += so;
                vo = (betao * vo + q.z) + bov; so = (vo >= 1.0f) ? 1.0f : 0.0f; vo = (vo >= 1.0f) ? 0.0f : vo; acc += so;
                vo = (betao * vo + q.w) + bov; so = (vo >= 1.0f) ? 1.0f : 0.0f; vo = (vo >= 1.0f) ? 0.0f : vo; acc += so;
            }
            vo  = __shfl(vo, ph);
            acc = __shfl(acc, ph);
        }
    };

    // ---- prologue: chunk 0 -> LDS buf0; chunk 1 -> staged regs
    sA = *(const float4*)(sgp);     sB = *(const float4*)(sgp + 4);
    nA = *(const float4*)(ngp);     nB = *(const float4*)(ngp + 4);
    pack_spk(spk[0]);
    {
        const float* ps = sgp + (size_t)1 * TC * SS;
        const float* pn = ngp + (size_t)1 * TC * SS;
        sA = *(const float4*)(ps);  sB = *(const float4*)(ps + 4);
        nA = *(const float4*)(pn);  nB = *(const float4*)(pn + 4);
    }
    __syncthreads();

    // A-frag addressing: row within mtile = lane&15; k-slot = lane>>4
    const int abase = hc * 128;
    const int koff0 = (((lane >> 4)    ) * 16) ^ ((hc & 7) << 4);
    const int koff1 = (((lane >> 4) + 4) * 16) ^ ((hc & 7) << 4);

    for (int c = 0; c < NC; ++c) {
        const int cur = c & 1;

        // pack chunk c+1 (staged) -> other buffer
        if (c + 1 < NC) pack_spk(spk[cur ^ 1]);

        // issue global loads for chunk c+2
        if (c + 2 < NC) {
            const float* ps = sgp + (size_t)(c + 2) * TC * SS;
            const float* pn = ngp + (size_t)(c + 2) * TC * SS;
            sA = *(const float4*)(ps);  sB = *(const float4*)(ps + 4);
            nA = *(const float4*)(pn);  nB = *(const float4*)(pn + 4);
        }

        // output LIF for chunk c-1 (lag-1)
        if (c > 0 && wave < 4) p4_step(rpart[cur ^ 1][wave]);

        // compute chunk c, software-pipelined A-frag reads
        const char* sp = spk[cur];
        f16x8 a0 = *(const f16x8*)(sp + abase + koff0);
        f16x8 a1 = *(const f16x8*)(sp + abase + koff1);
        #pragma unroll
        for (int tw = 0; tw < 4; ++tw) {
            f16x8 n0, n1;
            if (tw < 3) {
                const char* np = sp + abase + (tw + 1) * 2048;
                n0 = *(const f16x8*)(np + koff0);
                n1 = *(const f16x8*)(np + koff1);
            } else { n0 = a0; n1 = a1; }

            f32x4 ah0 = __builtin_amdgcn_mfma_f32_16x16x32_f16(a0, whi[0][0], zero4, 0, 0, 0);
            ah0       = __builtin_amdgcn_mfma_f32_16x16x32_f16(a1, whi[0][1], ah0,   0, 0, 0);
            f32x4 al0 = __builtin_amdgcn_mfma_f32_16x16x32_f16(a0, wlo[0][0], zero4, 0, 0, 0);
            al0       = __builtin_amdgcn_mfma_f32_16x16x32_f16(a1, wlo[0][1], al0,   0, 0, 0);
            f32x4 ah1 = __builtin_amdgcn_mfma_f32_16x16x32_f16(a0, whi[1][0], zero4, 0, 0, 0);
            ah1       = __builtin_amdgcn_mfma_f32_16x16x32_f16(a1, whi[1][1], ah1,   0, 0, 0);
            f32x4 al1 = __builtin_amdgcn_mfma_f32_16x16x32_f16(a0, wlo[1][0], zero4, 0, 0, 0);
            al1       = __builtin_amdgcn_mfma_f32_16x16x32_f16(a1, wlo[1][1], al1,   0, 0, 0);

            float rcv[4];
            #pragma unroll
            for (int r = 0; r < 4; ++r) {
                const float d0 = __builtin_fmaf(al0[r], 0x1p-11f, ah0[r]);
                const float d1 = __builtin_fmaf(al1[r], 0x1p-11f, ah1[r]);
                vh0 = __builtin_fmaf(betah, vh0, d0) + bh0;
                vh1 = __builtin_fmaf(betah, vh1, d1) + bh1;
                const bool c0 = (vh0 >= 1.0f);
                const bool c1 = (vh1 >= 1.0f);
                const float rr = (c0 ? wo0 : 0.0f) + (c1 ? wo1 : 0.0f);  // == s0*wo0+s1*wo1 exactly
                vh0 = c0 ? 0.0f : vh0;
                vh1 = c1 ? 0.0f : vh1;
                rcv[r] = rowsum16_asm(rr);
            }
            if ((lane & 15) == 0) {
                float4 rq = make_float4(rcv[0], rcv[1], rcv[2], rcv[3]);
                *(float4*)&rpart[cur][lane >> 4][wave][tw * 4] = rq;
            }
            a0 = n0; a1 = n1;
        }

        __syncthreads();   // spk writes + rpart writes all visible
    }

    // epilogue: output LIF for the last chunk, then write results
    if (wave < 4) {
        p4_step(rpart[(NC - 1) & 1][wave]);
        if (lane == 0) out[b0 + wave] = acc * (1.0f / (float)TT);
    }
}

extern "C" void kernel_launch(void* const* d_in, const int* in_sizes, int n_in,
                              void* d_out, int out_size, void* d_ws, size_t ws_size,
                              hipStream_t stream)
{
    const float* sensor = (const float*)d_in[0];
    const float* noise  = (const float*)d_in[1];
    const float* Wh     = (const float*)d_in[2];
    const float* bh     = (const float*)d_in[3];
    const float* Wo     = (const float*)d_in[4];
    const float* bo     = (const float*)d_in[5];
    float* out = (float*)d_out;

    const int B = in_sizes[0] / (TT * SS);   // 2048
    dim3 grid(B / BB), block(512);
    hipLaunchKernelGGL(snn_fused, grid, block, 0, stream,
                       sensor, noise, Wh, bh, Wo, bo, out);
}